// Round 4
// baseline (133.636 us; speedup 1.0000x reference)
//
#include <hip/hip_runtime.h>
#include <hip/hip_bf16.h>

// AbsolutePositionEncoding: out[b][s][e] = E[s>>3][e]
//   b in [0,64), s in [0,2048), e in [0,256), ALL FP32 (confirmed r3: passed,
//   absmax=0, dict order: d_in[0]=x unused, d_in[1]=E 512x256).
// Output: 134 MB pure broadcast-write -> write-BW-bound.
//
// R3 forensics: graph dur 131.5 us = ws-poison 83 + out-poison ~21 + restore
// ~1 + kernel ~26 us (kernel absent from top-5 dispatches, all fills).
// Kernel ~5.2 TB/s vs 6.4 TB/s demonstrated by the pure-fill kernel.
// Theory: 1 gather load per store steals VMEM issue slots / L1 cycles.
// Fix: load E once per thread, store to 8 batch images (batch dim is a pure
// replica — out[b] identical for all b). 8x fewer loads, 8x store ILP.

constexpr unsigned SEQ         = 2048;
constexpr unsigned VEC_PER_ROW = 256 / 4;                 // 64 float4 per (b,s) row
constexpr unsigned IMG_VEC     = SEQ * VEC_PER_ROW;       // 131072 float4 per batch image
constexpr unsigned B_PER_THD   = 8;                       // batches written per thread
constexpr unsigned TOTAL_THD   = IMG_VEC * (64 / B_PER_THD);  // 1,048,576 threads

__global__ __launch_bounds__(256)
void ape_broadcast_kernel(const float4* __restrict__ E, float4* __restrict__ out) {
    unsigned v  = blockIdx.x * blockDim.x + threadIdx.x;  // < 1,048,576
    unsigned e4 = v & (VEC_PER_ROW - 1);                  // wave spans e4 0..63 -> 1 KiB lines
    unsigned s  = (v >> 6) & (SEQ - 1);
    unsigned b8 = v >> 17;                                // batch group 0..7

    float4 val = E[(s >> 3) * VEC_PER_ROW + e4];          // one L1/L2-hit load, reused 8x

    unsigned base = b8 * (B_PER_THD * IMG_VEC) + s * VEC_PER_ROW + e4;
#pragma unroll
    for (unsigned i = 0; i < B_PER_THD; ++i)
        out[base + i * IMG_VEC] = val;                    // 8 coalesced 1 KiB wave-stores
}

extern "C" void kernel_launch(void* const* d_in, const int* in_sizes, int n_in,
                              void* d_out, int out_size, void* d_ws, size_t ws_size,
                              hipStream_t stream) {
    const float4* E = (const float4*)d_in[1];  // dict order: [0]=x (unused), [1]=E
    float4* out     = (float4*)d_out;

    constexpr unsigned BLOCK = 256;
    constexpr unsigned GRID  = TOTAL_THD / BLOCK;  // 4096 blocks
    ape_broadcast_kernel<<<GRID, BLOCK, 0, stream>>>(E, out);
}